// Round 1
// baseline (155.805 us; speedup 1.0000x reference)
//
#include <hip/hip_runtime.h>

// LearnableTD reverse affine suffix scan, v2.
// Theory-of-change vs v1 (512thr x 4elem, 2 barriers + serial tid0):
//   - 256 threads x 8 elems -> 4-wave blocks, ~6 resident blocks/CU
//     (vs 2.5 chunky 8-wave blocks): more independent load streams to
//     keep HBM issue busy during other blocks' scan/barrier phases.
//   - Single __syncthreads: cross-wave carry composed redundantly by
//     every thread from the 4 wave aggregates in LDS (<=3 broadcast
//     reads + FMAs, wave-uniform) instead of barrier + tid0 serial
//     loop + barrier.
//   - Odd-stride values loads / lam_out stores issued as align(4)
//     float4 (gfx950 supports unaligned global dwordx4; worst case the
//     compiler splits to dwords = old behavior).
//
// Affine maps, composed left-over-right ((L∘R).a = L.a + L.b*R.a):
//   b_t   = g*(1-d_t)*l_t
//   lam_t = [r_t + g*(1-d_t)*(1-l_t)*v_{t+1}] + b_t * lam_{t+1}
//   sum_t = [r_t]                             + b_t * sum_{t+1}

#define TPB 256
#define EPT 8

struct Aff { float aL, aS, b; };

__device__ inline Aff compose(const Aff& L, const Aff& R) {
    Aff o;
    o.aL = fmaf(L.b, R.aL, L.aL);
    o.aS = fmaf(L.b, R.aS, L.aS);
    o.b  = L.b * R.b;
    return o;
}

// align(4) float4: lets the backend emit unaligned global dwordx4 for the
// odd-stride (T+1) values rows; degrades to 4x dword if unsupported.
typedef float f4u __attribute__((ext_vector_type(4), aligned(4)));

// lambda[t] = 0.9 + 0.1*sigmoid(raw_lambd[start+t]) (batch-invariant).
__global__ void lam_precompute(const float* __restrict__ raw_lambd,
                               const int* __restrict__ start_p,
                               float* __restrict__ lam, int T) {
    int t = blockIdx.x * blockDim.x + threadIdx.x;
    if (t < T) lam[t] = 0.9f + 0.1f / (1.0f + __expf(-raw_lambd[start_p[0] + t]));
}

__global__ __launch_bounds__(TPB, 6)
void td_scan_kernel(const float* __restrict__ values,    // B x (T+1)
                    const float* __restrict__ rewards,   // B x T
                    const float* __restrict__ dones,     // B x T
                    const float* __restrict__ raw_gamma, // 1
                    const float* __restrict__ lam_arr,   // T (precomputed)
                    float* __restrict__ out,             // B*(T+1) lam ++ B*T sum
                    int B, int T)
{
    const int b    = blockIdx.x;
    const int tid  = threadIdx.x;
    const int lane = tid & 63;
    const int wave = tid >> 6;          // 0..3

    __shared__ float s_wAL[TPB / 64], s_wAS[TPB / 64], s_wB[TPB / 64];
    __shared__ float s_vT;

    const float g = 0.98f + 0.02f / (1.0f + __expf(-raw_gamma[0]));

    const float* vrow = values  + (size_t)b * (T + 1);
    const float* rrow = rewards + (size_t)b * T;
    const float* drow = dones   + (size_t)b * T;
    float* lam_out = out + (size_t)b * (T + 1);
    float* sum_out = out + (size_t)B * (T + 1) + (size_t)b * T;

    const int base = tid * EPT;
    const bool full = (base + EPT) <= T;

    // ---- all loads issued upfront ----
    float r[EPT], d[EPT], l[EPT], vn[EPT];
    if (full) {
        const float4 r0 = *(const float4*)(rrow + base);
        const float4 r1 = *(const float4*)(rrow + base + 4);
        const float4 d0 = *(const float4*)(drow + base);
        const float4 d1 = *(const float4*)(drow + base + 4);
        const float4 l0 = *(const float4*)(lam_arr + base);
        const float4 l1 = *(const float4*)(lam_arr + base + 4);
        const f4u    v0 = *(const f4u*)(vrow + base + 1);
        const f4u    v1 = *(const f4u*)(vrow + base + 5);
        r[0]=r0.x; r[1]=r0.y; r[2]=r0.z; r[3]=r0.w;
        r[4]=r1.x; r[5]=r1.y; r[6]=r1.z; r[7]=r1.w;
        d[0]=d0.x; d[1]=d0.y; d[2]=d0.z; d[3]=d0.w;
        d[4]=d1.x; d[5]=d1.y; d[6]=d1.z; d[7]=d1.w;
        l[0]=l0.x; l[1]=l0.y; l[2]=l0.z; l[3]=l0.w;
        l[4]=l1.x; l[5]=l1.y; l[6]=l1.z; l[7]=l1.w;
        vn[0]=v0[0]; vn[1]=v0[1]; vn[2]=v0[2]; vn[3]=v0[3];
        vn[4]=v1[0]; vn[5]=v1[1]; vn[6]=v1[2]; vn[7]=v1[3];
    } else {
        #pragma unroll
        for (int k = 0; k < EPT; ++k) {
            const int t = base + k;
            r[k]  = (t < T) ? rrow[t]     : 0.0f;
            d[k]  = (t < T) ? drow[t]     : 1.0f;
            l[k]  = (t < T) ? lam_arr[t]  : 0.0f;
            vn[k] = (t < T) ? vrow[t + 1] : 0.0f;
        }
    }
    if (tid == 0) {
        const float vT = vrow[T];
        s_vT = vT;
        lam_out[T] = vT;
    }

    // ---- per-thread affine maps + serial composite ----
    Aff M[EPT];
    #pragma unroll
    for (int k = 0; k < EPT; ++k) {
        const int t = base + k;
        if (t < T) {
            const float cont = g * (1.0f - d[k]);
            M[k].b  = cont * l[k];
            M[k].aL = fmaf(cont * (1.0f - l[k]), vn[k], r[k]);
            M[k].aS = r[k];
        } else {
            M[k].aL = 0.0f; M[k].aS = 0.0f; M[k].b = 1.0f;  // identity
        }
    }
    Aff C = M[EPT - 1];
    #pragma unroll
    for (int k = EPT - 2; k >= 0; --k) C = compose(M[k], C);

    // ---- inclusive suffix scan across the wave ----
    Aff S = C;
    #pragma unroll
    for (int dlt = 1; dlt < 64; dlt <<= 1) {
        Aff oth;
        oth.aL = __shfl_down(S.aL, dlt, 64);
        oth.aS = __shfl_down(S.aS, dlt, 64);
        oth.b  = __shfl_down(S.b,  dlt, 64);
        if (lane + dlt < 64) S = compose(S, oth);
    }
    // exclusive suffix (maps strictly right of this thread, within wave)
    Aff E;
    E.aL = __shfl_down(S.aL, 1, 64);
    E.aS = __shfl_down(S.aS, 1, 64);
    E.b  = __shfl_down(S.b,  1, 64);
    if (lane == 63) { E.aL = 0.0f; E.aS = 0.0f; E.b = 1.0f; }

    if (lane == 0) { s_wAL[wave] = S.aL; s_wAS[wave] = S.aS; s_wB[wave] = S.b; }
    __syncthreads();   // the ONLY block-wide barrier

    // ---- cross-wave carry: every thread composes the <=3 aggregates
    //      to its right (wave-uniform trip count, broadcast LDS reads) ----
    float cL = s_vT, cS = 0.0f;
    #pragma unroll
    for (int w = TPB / 64 - 1; w >= 1; --w) {
        if (w > wave) {
            const float wb = s_wB[w];
            cL = fmaf(wb, cL, s_wAL[w]);
            cS = fmaf(wb, cS, s_wAS[w]);
        }
    }

    // carry at this thread's right boundary
    float xL = fmaf(E.b, cL, E.aL);
    float xS = fmaf(E.b, cS, E.aS);

    // ---- apply through this thread's 8 elements, right-to-left ----
    float oL[EPT], oS[EPT];
    #pragma unroll
    for (int k = EPT - 1; k >= 0; --k) {
        xL = fmaf(M[k].b, xL, M[k].aL);
        xS = fmaf(M[k].b, xS, M[k].aS);
        oL[k] = xL; oS[k] = xS;
    }

    if (full) {
        *(float4*)(sum_out + base)     = make_float4(oS[0], oS[1], oS[2], oS[3]);
        *(float4*)(sum_out + base + 4) = make_float4(oS[4], oS[5], oS[6], oS[7]);
        f4u a, c;
        a[0]=oL[0]; a[1]=oL[1]; a[2]=oL[2]; a[3]=oL[3];
        c[0]=oL[4]; c[1]=oL[5]; c[2]=oL[6]; c[3]=oL[7];
        *(f4u*)(lam_out + base)     = a;   // 4B-aligned rows: unaligned dwordx4
        *(f4u*)(lam_out + base + 4) = c;
    } else {
        #pragma unroll
        for (int k = 0; k < EPT; ++k) {
            const int t = base + k;
            if (t < T) { lam_out[t] = oL[k]; sum_out[t] = oS[k]; }
        }
    }
}

extern "C" void kernel_launch(void* const* d_in, const int* in_sizes, int n_in,
                              void* d_out, int out_size, void* d_ws, size_t ws_size,
                              hipStream_t stream) {
    const float* values    = (const float*)d_in[0];
    const float* rewards   = (const float*)d_in[1];
    const float* dones     = (const float*)d_in[2];
    const float* raw_gamma = (const float*)d_in[3];
    const float* raw_lambd = (const float*)d_in[4];
    const int*   start_idx = (const int*)d_in[5];
    float* out = (float*)d_out;
    float* lam_arr = (float*)d_ws;

    const int n_values  = in_sizes[0];   // B*(T+1)
    const int n_rewards = in_sizes[1];   // B*T
    const int B = n_values - n_rewards;
    const int T = n_rewards / B;

    lam_precompute<<<(T + 255) / 256, 256, 0, stream>>>(raw_lambd, start_idx, lam_arr, T);
    td_scan_kernel<<<B, TPB, 0, stream>>>(values, rewards, dones, raw_gamma,
                                          lam_arr, out, B, T);
}